// Round 4
// baseline (6937.546 us; speedup 1.0000x reference)
//
#include <hip/hip_runtime.h>

typedef unsigned short u16;
using s8v = __attribute__((ext_vector_type(8))) short;
using f4v = __attribute__((ext_vector_type(4))) float;

#define B_   32
#define N_   64
#define T_   128
#define D_   64
#define EMB_ 128
#define H_   256
#define E_   512
#define G3_  768

#define MFMA16(a, b, c) __builtin_amdgcn_mfma_f32_16x16x32_bf16(a, b, c, 0, 0, 0)

__device__ __forceinline__ float bf2f(u16 v) {
  union { unsigned u; float f; } x; x.u = ((unsigned)v) << 16; return x.f;
}
__device__ __forceinline__ u16 f2bf(float f) {
  union { float f; unsigned u; } x; x.f = f;
  unsigned r = x.u + 0x7fffu + ((x.u >> 16) & 1u);
  return (u16)(r >> 16);
}
// dual-mode float input load: bf=1 -> storage is bf16, bf=0 -> float32
__device__ __forceinline__ float ldin(const void* p, size_t i, int bf) {
  return bf ? bf2f(((const u16*)p)[i]) : ((const float*)p)[i];
}
__device__ __forceinline__ float clamp30(float x) {
  return fminf(30.f, fmaxf(-30.f, x));
}
__device__ __forceinline__ float sigm_f(float x) {
  return __builtin_amdgcn_rcpf(1.f + __expf(-clamp30(x)));
}
__device__ __forceinline__ float tanh_f(float x) {
  return 1.f - 2.f * __builtin_amdgcn_rcpf(1.f + __expf(2.f * clamp30(x)));
}

// Persistent kernel: grid = 256 blocks = (node 0..63) x (col-quarter p 0..3).
// Block: all 32 batch rows, owns H-cols [64p,64p+64) (x3 gates) and EMB-cols
// [32p,32p+32). 8 waves x 512 thr -> 256-VGPR budget: all weights in VGPRs,
// zero spill. ge computed redundantly (full) per block to avoid one exchange;
// h exchanged across the 4 sibling blocks via global + per-node flag.
__global__ __launch_bounds__(512, 2) void ggru_kernel(
    const void* __restrict__ x, const int* __restrict__ fi,
    const int* __restrict__ esrc, const int* __restrict__ edst,
    const void* __restrict__ Winit, const void* __restrict__ binit,
    const void* __restrict__ Wg, const void* __restrict__ bg,
    const void* __restrict__ Wih, const void* __restrict__ Whh,
    const void* __restrict__ bih, const void* __restrict__ bhh,
    const void* __restrict__ Wlast, const void* __restrict__ blast,
    float* __restrict__ out, int* __restrict__ barrier_base,
    float* __restrict__ ebuf, u16* __restrict__ hX)
{
  const int node = blockIdx.x >> 2;
  const int p    = blockIdx.x & 3;
  const int tid  = threadIdx.x;
  const int w    = tid >> 6;            // wave 0..7
  const int lane = tid & 63;
  const int quad = lane >> 4;           // 0..3
  const int c    = lane & 15;

  __shared__ short sEdge[E_];
  __shared__ int   sCnt;
  __shared__ int   sFi[32];
  __shared__ __align__(16) u16 xl[32][72];     // x_t (stride 144B, 16B-mult)
  __shared__ __align__(16) u16 aggl[32][136];  // agg (272B rows)
  __shared__ __align__(16) u16 gelF[32][264];  // full ge (528B rows)
  __shared__ __align__(16) u16 hlF[32][264];   // full h

  // ---- runtime dtype probe (bf16 vs f32 storage), proven in R3 ----
  int plaus = 0;
  {
    const u16* q = (const u16*)Wg;
#pragma unroll 8
    for (int i = 0; i < 512; ++i) {
      float a = fabsf(bf2f(q[i]));
      plaus += (a > 1e-4f && a < 0.3f) ? 1 : 0;
    }
  }
  const int bf = (plaus >= 450) ? 1 : 0;

  if (tid == 0) sCnt = 0;
  if (tid < 32) sFi[tid] = fi[tid] - 1;
  __syncthreads();
  // exactly one edge per thread (E_ == 512 == blockDim)
  if (edst[tid] == node) {
    int q = atomicAdd(&sCnt, 1);
    sEdge[q] = (short)esrc[tid];
  }

  // ---- weights -> VGPR MFMA B-fragments (col=lane&15, k=quad*8+j) ----
  // phase B: wave w owns ge cols [32w, 32w+32), both row-halves
  s8v Bg_[2][4];
#pragma unroll
  for (int ct = 0; ct < 2; ++ct)
#pragma unroll
    for (int kt = 0; kt < 4; ++kt) {
      s8v f;
#pragma unroll
      for (int j = 0; j < 8; ++j)
        f[j] = (short)f2bf(ldin(Wg, (size_t)(kt * 32 + quad * 8 + j) * H_ + 32 * w + 16 * ct + c, bf));
      Bg_[ct][kt] = f;
    }
  // phase C: g = w>>1, r = w&1; H-col = 64p + 16g + c
  const int hcol = 64 * p + 16 * (w >> 1) + c;
  s8v Bih_[3][2], Bhh_[3][8];
#pragma unroll
  for (int gt = 0; gt < 3; ++gt) {
    const size_t bih_base = (size_t)node * G3_ * D_ + (size_t)(gt * H_ + hcol) * D_;
    const size_t bhh_base = (size_t)node * G3_ * H_ + (size_t)(gt * H_ + hcol) * H_;
#pragma unroll
    for (int kt = 0; kt < 2; ++kt) {
      s8v f;
#pragma unroll
      for (int j = 0; j < 8; ++j)
        f[j] = (short)f2bf(ldin(Wih, bih_base + kt * 32 + quad * 8 + j, bf));
      Bih_[gt][kt] = f;
    }
#pragma unroll
    for (int kt = 0; kt < 8; ++kt) {
      s8v f;
#pragma unroll
      for (int j = 0; j < 8; ++j)
        f[j] = (short)f2bf(ldin(Whh, bhh_base + kt * 32 + quad * 8 + j, bf));
      Bhh_[gt][kt] = f;
    }
  }
  // phase D: waves 0..3: EMB-col = 32p + 16*(w>>1) + c
  const int ecol = 32 * p + 16 * (w >> 1) + c;
  s8v Bl_[8];
  if (w < 4) {
    const size_t bl_base = (size_t)node * EMB_ * H_ + (size_t)ecol * H_;
#pragma unroll
    for (int kt = 0; kt < 8; ++kt) {
      s8v f;
#pragma unroll
      for (int j = 0; j < 8; ++j)
        f[j] = (short)f2bf(ldin(Wlast, bl_base + kt * 32 + quad * 8 + j, bf));
      Bl_[kt] = f;
    }
  }
  float bgc[2];
#pragma unroll
  for (int ct = 0; ct < 2; ++ct) bgc[ct] = ldin(bg, 32 * w + 16 * ct + c, bf);
  float bihv[3], bhhv[3];
#pragma unroll
  for (int gt = 0; gt < 3; ++gt) {
    bihv[gt] = ldin(bih, (size_t)node * G3_ + gt * H_ + hcol, bf);
    bhhv[gt] = ldin(bhh, (size_t)node * G3_ + gt * H_ + hcol, bf);
  }
  const float blc = (w < 4) ? ldin(blast, (size_t)node * EMB_ + ecol, bf) : 0.f;

  // ---- x0 tile + e0 = x0 @ Winit[n]^T + binit (block's 32 EMB cols) ----
  {
    const int row = tid >> 4, d0 = (tid & 15) * 4;
#pragma unroll
    for (int k = 0; k < 4; ++k)
      xl[row][d0 + k] = f2bf(ldin(x, ((size_t)row * N_ + node) * (T_ * D_) + d0 + k, bf));
  }
  __syncthreads();
  const int cnt = sCnt;
  const float invdeg = 1.0f / (float)(cnt + 1);
#pragma unroll
  for (int rep = 0; rep < 2; ++rep) {
    const int o = tid + rep * 512;
    const int row = o >> 5, f = 32 * p + (o & 31);
    float s = ldin(binit, (size_t)node * EMB_ + f, bf);
    const size_t wb = ((size_t)node * EMB_ + f) * D_;
#pragma unroll 8
    for (int d = 0; d < D_; ++d) s += bf2f(xl[row][d]) * ldin(Winit, wb + d, bf);
    ebuf[(size_t)row * (N_ * EMB_) + node * EMB_ + f] = s;  // parity 0
  }

  int* gctr  = barrier_base;       // global barrier counter
  int* hflag = barrier_base + 64;  // per-node sibling flags
  int phase = 0;

#pragma unroll 1
  for (int t = 0; t < T_; ++t) {
    // ---- global barrier: e(t) fully written & visible; skew <= 1 step ----
    __syncthreads();
    ++phase;
    if (tid == 0) {
      __threadfence();
      atomicAdd(gctr, 1);
      while (__hip_atomic_load(gctr, __ATOMIC_RELAXED, __HIP_MEMORY_SCOPE_AGENT) < 256 * phase)
        __builtin_amdgcn_s_sleep(2);
      __threadfence();
    }
    __syncthreads();
    const float* ec = ebuf + (size_t)(t & 1) * (B_ * N_ * EMB_);
    float*       en = ebuf + (size_t)((t + 1) & 1) * (B_ * N_ * EMB_);

    // ---- phase A: x_t tile + GCN mean-aggregate (full 32x128) ----
    {
      const int row = tid >> 4, d0 = (tid & 15) * 4;
#pragma unroll
      for (int k = 0; k < 4; ++k)
        xl[row][d0 + k] = f2bf(ldin(x, ((size_t)row * N_ + node) * (T_ * D_) + (size_t)t * D_ + d0 + k, bf));
    }
    {
      const int row = tid >> 4, f0 = (tid & 15) * 8;
      const float* base = ec + (size_t)row * (N_ * EMB_) + f0;
      float s[8];
#pragma unroll
      for (int k = 0; k < 8; ++k) s[k] = base[node * EMB_ + k];
      for (int i = 0; i < cnt; ++i) {
        const float* sp = base + (int)sEdge[i] * EMB_;
#pragma unroll
        for (int k = 0; k < 8; ++k) s[k] += sp[k];
      }
      s8v pk;
#pragma unroll
      for (int k = 0; k < 8; ++k) pk[k] = (short)f2bf(s[k] * invdeg);
      *(s8v*)&aggl[row][f0] = pk;
    }
    __syncthreads();

    // ---- phase B: full ge = tanh(agg @ Wg + bg); wave w -> cols [32w,+32) ----
#pragma unroll
    for (int rt = 0; rt < 2; ++rt) {
      s8v a[4];
#pragma unroll
      for (int kt = 0; kt < 4; ++kt) a[kt] = *(const s8v*)&aggl[16 * rt + c][kt * 32 + quad * 8];
#pragma unroll
      for (int ct = 0; ct < 2; ++ct) {
        f4v acc = {0.f, 0.f, 0.f, 0.f};
#pragma unroll
        for (int kt = 0; kt < 4; ++kt) acc = MFMA16(a[kt], Bg_[ct][kt], acc);
#pragma unroll
        for (int i = 0; i < 4; ++i)
          gelF[16 * rt + quad * 4 + i][32 * w + 16 * ct + c] = f2bf(tanh_f(acc[i] + bgc[ct]));
      }
    }
    __syncthreads();

    // ---- phase C: GRU gates for (rows 16r.., H-cols hcol); write h slice ----
    {
      const int r = w & 1;
      f4v aR = {0,0,0,0}, aZ = {0,0,0,0}, aXn = {0,0,0,0}, aHn = {0,0,0,0};
#pragma unroll
      for (int kt = 0; kt < 2; ++kt) {
        s8v a = *(const s8v*)&xl[16 * r + c][kt * 32 + quad * 8];
        aR  = MFMA16(a, Bih_[0][kt], aR);
        aZ  = MFMA16(a, Bih_[1][kt], aZ);
        aXn = MFMA16(a, Bih_[2][kt], aXn);
      }
#pragma unroll
      for (int kt = 0; kt < 8; ++kt) {
        s8v a = *(const s8v*)&gelF[16 * r + c][kt * 32 + quad * 8];
        aR  = MFMA16(a, Bhh_[0][kt], aR);
        aZ  = MFMA16(a, Bhh_[1][kt], aZ);
        aHn = MFMA16(a, Bhh_[2][kt], aHn);
      }
      u16* hXw = hX + ((size_t)(t & 1) * N_ + node) * (32 * 256);
#pragma unroll
      for (int i = 0; i < 4; ++i) {
        const int row = 16 * r + quad * 4 + i;
        float ge = bf2f(gelF[row][hcol]);
        float r_ = sigm_f(aR[i] + bihv[0] + bhhv[0]);
        float z_ = sigm_f(aZ[i] + bihv[1] + bhhv[1]);
        float ng = tanh_f(aXn[i] + bihv[2] + r_ * (aHn[i] + bhhv[2]));
        hXw[row * 256 + hcol] = f2bf((1.f - z_) * ng + z_ * ge);
      }
    }
    // ---- h exchange across 4 sibling blocks (per-node flag) ----
    __syncthreads();
    if (tid == 0) {
      __threadfence();
      atomicAdd(hflag + node, 1);
      while (__hip_atomic_load(hflag + node, __ATOMIC_RELAXED, __HIP_MEMORY_SCOPE_AGENT) < 4 * (t + 1))
        __builtin_amdgcn_s_sleep(2);
      __threadfence();
    }
    __syncthreads();
    {
      const u16* hXw = hX + ((size_t)(t & 1) * N_ + node) * (32 * 256);
      const int row = tid >> 4, f0 = (tid & 15) * 16;
      s8v v0 = *(const s8v*)(hXw + row * 256 + f0);
      s8v v1 = *(const s8v*)(hXw + row * 256 + f0 + 8);
      *(s8v*)&hlF[row][f0] = v0;
      *(s8v*)&hlF[row][f0 + 8] = v1;
    }
    __syncthreads();

    // ---- phase D: e_new = tanh(h @ Wlast^T + blast) for 32 block EMB-cols ----
    if (w < 4) {
      const int r = w & 1;
      f4v aE = {0,0,0,0};
#pragma unroll
      for (int kt = 0; kt < 8; ++kt) {
        s8v a = *(const s8v*)&hlF[16 * r + c][kt * 32 + quad * 8];
        aE = MFMA16(a, Bl_[kt], aE);
      }
#pragma unroll
      for (int i = 0; i < 4; ++i) {
        const int row = 16 * r + quad * 4 + i;
        float v = tanh_f(aE[i] + blc);
        const size_t off = (size_t)row * (N_ * EMB_) + node * EMB_ + ecol;
        en[off] = v;
        if (sFi[row] == t) out[off] = v;
      }
    }
  }
}

extern "C" void kernel_launch(void* const* d_in, const int* in_sizes, int n_in,
                              void* d_out, int out_size, void* d_ws, size_t ws_size,
                              hipStream_t stream) {
  const void* x     = d_in[0];
  const int*  fi    = (const int*)d_in[1];
  const int*  esrc  = (const int*)d_in[2];
  const int*  edst  = (const int*)d_in[3];
  const void* Winit = d_in[4];
  const void* binit = d_in[5];
  const void* Wg    = d_in[6];
  const void* bg    = d_in[7];
  const void* Wih   = d_in[8];
  const void* Whh   = d_in[9];
  const void* bih   = d_in[10];
  const void* bhh   = d_in[11];
  const void* Wlast = d_in[12];
  const void* blast = d_in[13];

  // d_ws: [0,4096) counters+flags (zeroed); [4K, 4K+2MB) ebuf f32 x2 parity;
  // then hX bf16 x2 parity (2 MB)
  int*   barrier_base = (int*)d_ws;
  float* ebuf = (float*)((char*)d_ws + 4096);
  u16*   hX   = (u16*)((char*)d_ws + 4096 + 2u * B_ * N_ * EMB_ * 4u);
  hipMemsetAsync(d_ws, 0, 4096, stream);

  ggru_kernel<<<256, 512, 0, stream>>>(
      x, fi, esrc, edst, Winit, binit, Wg, bg, Wih, Whh, bih, bhh,
      Wlast, blast, (float*)d_out, barrier_base, ebuf, hX);
}

// Round 5
// 5213.298 us; speedup vs baseline: 1.3307x; 1.3307x over previous
//
#include <hip/hip_runtime.h>

typedef unsigned short u16;
using s8v = __attribute__((ext_vector_type(8))) short;
using s4v = __attribute__((ext_vector_type(4))) short;
using f4v = __attribute__((ext_vector_type(4))) float;

#define B_   32
#define N_   64
#define T_   128
#define D_   64
#define EMB_ 128
#define H_   256
#define E_   512
#define G3_  768

#define MFMA16(a, b, c) __builtin_amdgcn_mfma_f32_16x16x32_bf16(a, b, c, 0, 0, 0)
// pin a 128-bit fragment into the AGPR half of the unified file
#define PIN_A(v) asm volatile("" : "+a"(v))

__device__ __forceinline__ float bf2f(u16 v) {
  union { unsigned u; float f; } x; x.u = ((unsigned)v) << 16; return x.f;
}
__device__ __forceinline__ u16 f2bf(float f) {
  union { float f; unsigned u; } x; x.f = f;
  unsigned r = x.u + 0x7fffu + ((x.u >> 16) & 1u);
  return (u16)(r >> 16);
}
// dual-mode float input load: bf=1 -> storage is bf16, bf=0 -> float32
__device__ __forceinline__ float ldin(const void* p, size_t i, int bf) {
  return bf ? bf2f(((const u16*)p)[i]) : ((const float*)p)[i];
}
__device__ __forceinline__ float clamp30(float x) {
  return fminf(30.f, fmaxf(-30.f, x));
}
__device__ __forceinline__ float sigm_f(float x) {
  return __builtin_amdgcn_rcpf(1.f + __expf(-clamp30(x)));
}
__device__ __forceinline__ float tanh_f(float x) {
  return 1.f - 2.f * __builtin_amdgcn_rcpf(1.f + __expf(2.f * clamp30(x)));
}

// Persistent kernel: 64 blocks (one per node) x 1024 threads (16 waves).
// Block owns all 32 batch rows and ALL columns for its node: ge/h/x tiles are
// block-local LDS; the only cross-block dependency is e -> ONE 64-block
// barrier per step. Weights live in AGPRs (pinned) -> zero scratch spill.
// waves_per_eu(4,4): exactly 4 waves/SIMD -> 512 unified regs/wave budget.
__global__ __attribute__((amdgpu_waves_per_eu(4, 4))) __launch_bounds__(1024)
void ggru_kernel(
    const void* __restrict__ x, const int* __restrict__ fi,
    const int* __restrict__ esrc, const int* __restrict__ edst,
    const void* __restrict__ Winit, const void* __restrict__ binit,
    const void* __restrict__ Wg, const void* __restrict__ bg,
    const void* __restrict__ Wih, const void* __restrict__ Whh,
    const void* __restrict__ bih, const void* __restrict__ bhh,
    const void* __restrict__ Wlast, const void* __restrict__ blast,
    float* __restrict__ out, int* __restrict__ gctr,
    float* __restrict__ ebuf)
{
  const int node = blockIdx.x;
  const int tid  = threadIdx.x;
  const int w    = tid >> 6;            // wave 0..15
  const int lane = tid & 63;
  const int quad = lane >> 4;           // 0..3
  const int c    = lane & 15;
  const int colw = (w << 4) + c;        // wave's H/ge column 0..255
  const int rhD  = w & 1;               // phase-D row half
  const int ecol = 16 * (w >> 1) + c;   // phase-D EMB column 0..127

  __shared__ short sEdge[E_];
  __shared__ int   sCnt;
  __shared__ int   sFi[32];
  __shared__ __align__(16) u16 xl[32][72];     // x_t tile
  __shared__ __align__(16) u16 aggl[32][136];  // GCN aggregate
  __shared__ __align__(16) u16 gelF[32][264];  // full ge
  __shared__ __align__(16) u16 hlF[32][264];   // full h

  // ---- runtime dtype probe (bf16 vs f32 storage), proven in R3 ----
  int plaus = 0;
  {
    const u16* q = (const u16*)Wg;
#pragma unroll 8
    for (int i = 0; i < 512; ++i) {
      float a = fabsf(bf2f(q[i]));
      plaus += (a > 1e-4f && a < 0.3f) ? 1 : 0;
    }
  }
  const int bf = (plaus >= 450) ? 1 : 0;

  if (tid == 0) sCnt = 0;
  if (tid < 32) sFi[tid] = fi[tid] - 1;
  __syncthreads();
  if (tid < E_) {
    if (edst[tid] == node) {
      int q = atomicAdd(&sCnt, 1);
      sEdge[q] = (short)esrc[tid];
    }
  }

  // ---- weights -> MFMA B-fragments pinned in AGPRs (once) ----
  // B-frag layout (16x16x32): n = lane&15, k = quad*8 + j
  s8v Bg_[4];        // Wg (128->256): wave w cols [16w,16w+16)
#pragma unroll
  for (int kt = 0; kt < 4; ++kt) {
    s8v f;
#pragma unroll
    for (int j = 0; j < 8; ++j)
      f[j] = (short)f2bf(ldin(Wg, (size_t)(kt * 32 + quad * 8 + j) * H_ + colw, bf));
    Bg_[kt] = f; PIN_A(Bg_[kt]);
  }
  s8v Bih_[3][2], Bhh_[3][8];
#pragma unroll
  for (int gt = 0; gt < 3; ++gt) {
    const size_t bih_base = (size_t)node * G3_ * D_ + (size_t)(gt * H_ + colw) * D_;
    const size_t bhh_base = (size_t)node * G3_ * H_ + (size_t)(gt * H_ + colw) * H_;
#pragma unroll
    for (int kt = 0; kt < 2; ++kt) {
      s8v f;
#pragma unroll
      for (int j = 0; j < 8; ++j)
        f[j] = (short)f2bf(ldin(Wih, bih_base + kt * 32 + quad * 8 + j, bf));
      Bih_[gt][kt] = f; PIN_A(Bih_[gt][kt]);
    }
#pragma unroll
    for (int kt = 0; kt < 8; ++kt) {
      s8v f;
#pragma unroll
      for (int j = 0; j < 8; ++j)
        f[j] = (short)f2bf(ldin(Whh, bhh_base + kt * 32 + quad * 8 + j, bf));
      Bhh_[gt][kt] = f; PIN_A(Bhh_[gt][kt]);
    }
  }
  s8v Bl_[8];        // W_last: all 16 waves (rh = w&1, ecol-tile = w>>1)
  {
    const size_t bl_base = (size_t)node * EMB_ * H_ + (size_t)ecol * H_;
#pragma unroll
    for (int kt = 0; kt < 8; ++kt) {
      s8v f;
#pragma unroll
      for (int j = 0; j < 8; ++j)
        f[j] = (short)f2bf(ldin(Wlast, bl_base + kt * 32 + quad * 8 + j, bf));
      Bl_[kt] = f; PIN_A(Bl_[kt]);
    }
  }
  const float bgc  = ldin(bg, colw, bf);
  float bihv[3], bhhv[3];
#pragma unroll
  for (int gt = 0; gt < 3; ++gt) {
    bihv[gt] = ldin(bih, (size_t)node * G3_ + gt * H_ + colw, bf);
    bhhv[gt] = ldin(bhh, (size_t)node * G3_ + gt * H_ + colw, bf);
  }
  const float blc = ldin(blast, (size_t)node * EMB_ + ecol, bf);

  // ---- x0 tile + e0 = x0 @ Winit[n]^T + binit (full 32x128) ----
  {
    const int row = tid >> 5, d0 = (tid & 31) * 2;
    xl[row][d0]     = f2bf(ldin(x, ((size_t)row * N_ + node) * (T_ * D_) + d0, bf));
    xl[row][d0 + 1] = f2bf(ldin(x, ((size_t)row * N_ + node) * (T_ * D_) + d0 + 1, bf));
  }
  __syncthreads();
  const int cnt = sCnt;
  const float invdeg = 1.0f / (float)(cnt + 1);
#pragma unroll
  for (int rep = 0; rep < 4; ++rep) {
    const int o = tid + rep * 1024;
    const int row = o >> 7, f = o & 127;
    float s = ldin(binit, (size_t)node * EMB_ + f, bf);
    const size_t wb = ((size_t)node * EMB_ + f) * D_;
#pragma unroll 8
    for (int d = 0; d < D_; ++d) s += bf2f(xl[row][d]) * ldin(Winit, wb + d, bf);
    ebuf[(size_t)row * (N_ * EMB_) + node * EMB_ + f] = s;  // parity 0
  }

  int phase = 0;
#pragma unroll 1
  for (int t = 0; t < T_; ++t) {
    // ---- global barrier (64 blocks): e(t) written & visible; skew <= 1 ----
    __syncthreads();
    ++phase;
    if (tid == 0) {
      __threadfence();
      atomicAdd(gctr, 1);
      while (__hip_atomic_load(gctr, __ATOMIC_RELAXED, __HIP_MEMORY_SCOPE_AGENT) < 64 * phase)
        __builtin_amdgcn_s_sleep(2);
      __threadfence();
    }
    __syncthreads();
    const float* ec = ebuf + (size_t)(t & 1) * (B_ * N_ * EMB_);
    float*       en = ebuf + (size_t)((t + 1) & 1) * (B_ * N_ * EMB_);

    // ---- phase A: x_t tile + GCN mean-aggregate (full 32x128) ----
    {
      const int row = tid >> 5, d0 = (tid & 31) * 2;
      xl[row][d0]     = f2bf(ldin(x, ((size_t)row * N_ + node) * (T_ * D_) + (size_t)t * D_ + d0, bf));
      xl[row][d0 + 1] = f2bf(ldin(x, ((size_t)row * N_ + node) * (T_ * D_) + (size_t)t * D_ + d0 + 1, bf));
    }
    {
      const int row = tid >> 5, f0 = (tid & 31) * 4;
      const float* base = ec + (size_t)row * (N_ * EMB_) + f0;
      f4v s = *(const f4v*)(base + node * EMB_);
      for (int i = 0; i < cnt; ++i) {
        f4v v = *(const f4v*)(base + (int)sEdge[i] * EMB_);
        s += v;
      }
      s4v pk;
#pragma unroll
      for (int k = 0; k < 4; ++k) pk[k] = (short)f2bf(s[k] * invdeg);
      *(s4v*)&aggl[row][f0] = pk;
    }
    __syncthreads();

    // ---- phase B: ge = tanh(agg @ Wg + bg); wave w -> cols [16w,16w+16) ----
    float gev[2][4];
#pragma unroll
    for (int rh = 0; rh < 2; ++rh) {
      f4v acc = {0.f, 0.f, 0.f, 0.f};
#pragma unroll
      for (int kt = 0; kt < 4; ++kt) {
        s8v a = *(const s8v*)&aggl[16 * rh + c][kt * 32 + quad * 8];
        acc = MFMA16(a, Bg_[kt], acc);
      }
#pragma unroll
      for (int i = 0; i < 4; ++i) {
        gev[rh][i] = tanh_f(acc[i] + bgc);
        gelF[16 * rh + quad * 4 + i][colw] = f2bf(gev[rh][i]);
      }
    }
    __syncthreads();

    // ---- phase C: GRU gates (wave w: H-col colw, both row halves) ----
#pragma unroll
    for (int rh = 0; rh < 2; ++rh) {
      f4v aR = {0,0,0,0}, aZ = {0,0,0,0}, aXn = {0,0,0,0}, aHn = {0,0,0,0};
#pragma unroll
      for (int kt = 0; kt < 2; ++kt) {
        s8v a = *(const s8v*)&xl[16 * rh + c][kt * 32 + quad * 8];
        aR  = MFMA16(a, Bih_[0][kt], aR);
        aZ  = MFMA16(a, Bih_[1][kt], aZ);
        aXn = MFMA16(a, Bih_[2][kt], aXn);
      }
#pragma unroll
      for (int kt = 0; kt < 8; ++kt) {
        s8v a = *(const s8v*)&gelF[16 * rh + c][kt * 32 + quad * 8];
        aR  = MFMA16(a, Bhh_[0][kt], aR);
        aZ  = MFMA16(a, Bhh_[1][kt], aZ);
        aHn = MFMA16(a, Bhh_[2][kt], aHn);
      }
#pragma unroll
      for (int i = 0; i < 4; ++i) {
        float r_ = sigm_f(aR[i] + bihv[0] + bhhv[0]);
        float z_ = sigm_f(aZ[i] + bihv[1] + bhhv[1]);
        float ng = tanh_f(aXn[i] + bihv[2] + r_ * (aHn[i] + bhhv[2]));
        float h  = (1.f - z_) * ng + z_ * gev[rh][i];
        hlF[16 * rh + quad * 4 + i][colw] = f2bf(h);
      }
    }
    __syncthreads();

    // ---- phase D: e_new = tanh(h @ Wlast^T + blast); all 16 waves ----
    {
      f4v aE = {0,0,0,0};
#pragma unroll
      for (int kt = 0; kt < 8; ++kt) {
        s8v a = *(const s8v*)&hlF[16 * rhD + c][kt * 32 + quad * 8];
        aE = MFMA16(a, Bl_[kt], aE);
      }
#pragma unroll
      for (int i = 0; i < 4; ++i) {
        const int row = 16 * rhD + quad * 4 + i;
        float v = tanh_f(aE[i] + blc);
        const size_t off = (size_t)row * (N_ * EMB_) + node * EMB_ + ecol;
        en[off] = v;
        if (sFi[row] == t) out[off] = v;
      }
    }
  }
}

extern "C" void kernel_launch(void* const* d_in, const int* in_sizes, int n_in,
                              void* d_out, int out_size, void* d_ws, size_t ws_size,
                              hipStream_t stream) {
  const void* x     = d_in[0];
  const int*  fi    = (const int*)d_in[1];
  const int*  esrc  = (const int*)d_in[2];
  const int*  edst  = (const int*)d_in[3];
  const void* Winit = d_in[4];
  const void* binit = d_in[5];
  const void* Wg    = d_in[6];
  const void* bg    = d_in[7];
  const void* Wih   = d_in[8];
  const void* Whh   = d_in[9];
  const void* bih   = d_in[10];
  const void* bhh   = d_in[11];
  const void* Wlast = d_in[12];
  const void* blast = d_in[13];

  // d_ws: [0,4096) barrier counter (zeroed); [4K, 4K+2MB) ebuf f32 x2 parity
  int*   gctr = (int*)d_ws;
  float* ebuf = (float*)((char*)d_ws + 4096);
  hipMemsetAsync(d_ws, 0, 4096, stream);

  ggru_kernel<<<64, 1024, 0, stream>>>(
      x, fi, esrc, edst, Winit, binit, Wg, bg, Wih, Whh, bih, bhh,
      Wlast, blast, (float*)d_out, gctr, ebuf);
}

// Round 6
// 3125.244 us; speedup vs baseline: 2.2198x; 1.6681x over previous
//
#include <hip/hip_runtime.h>

typedef unsigned short u16;
using s8v = __attribute__((ext_vector_type(8))) short;
using f4v = __attribute__((ext_vector_type(4))) float;

#define B_   32
#define N_   64
#define T_   128
#define D_   64
#define EMB_ 128
#define H_   256
#define E_   512
#define G3_  768

#define MFMA16(a, b, c) __builtin_amdgcn_mfma_f32_16x16x32_bf16(a, b, c, 0, 0, 0)

__device__ __forceinline__ float bf2f(u16 v) {
  union { unsigned u; float f; } x; x.u = ((unsigned)v) << 16; return x.f;
}
__device__ __forceinline__ u16 f2bf(float f) {
  union { float f; unsigned u; } x; x.f = f;
  unsigned r = x.u + 0x7fffu + ((x.u >> 16) & 1u);
  return (u16)(r >> 16);
}
// dual-mode float input load: bf=1 -> storage is bf16, bf=0 -> float32
__device__ __forceinline__ float ldin(const void* p, size_t i, int bf) {
  return bf ? bf2f(((const u16*)p)[i]) : ((const float*)p)[i];
}
__device__ __forceinline__ float clamp30(float x) {
  return fminf(30.f, fmaxf(-30.f, x));
}
__device__ __forceinline__ float sigm_f(float x) {
  return __builtin_amdgcn_rcpf(1.f + __expf(-clamp30(x)));
}
__device__ __forceinline__ float tanh_f(float x) {
  return 1.f - 2.f * __builtin_amdgcn_rcpf(1.f + __expf(2.f * clamp30(x)));
}

// 128 persistent blocks = (node 0..63) x (sibling s 0..1). 512 thr = 8 waves.
// waves_per_eu(2,2) -> 2 waves/SIMD -> 256-reg/wave budget: all weight
// fragments register-resident, zero spill. Sibling s owns H-cols
// [128s,128s+128): phase C produces exactly the h-cols that are s's K-range
// in phase D, so e_new is exchanged as PARTIAL SUMS (s=0 adds bias) and the
// consumer applies tanh -> no sibling sync; ONE global barrier per step.
__global__ __launch_bounds__(512) __attribute__((amdgpu_waves_per_eu(2, 2)))
void ggru_kernel(
    const void* __restrict__ x, const int* __restrict__ fi,
    const int* __restrict__ esrc, const int* __restrict__ edst,
    const void* __restrict__ Winit, const void* __restrict__ binit,
    const void* __restrict__ Wg, const void* __restrict__ bg,
    const void* __restrict__ Wih, const void* __restrict__ Whh,
    const void* __restrict__ bih, const void* __restrict__ bhh,
    const void* __restrict__ Wlast, const void* __restrict__ blast,
    float* __restrict__ out, int* __restrict__ gctr,
    float* __restrict__ ep)
{
  const int node = blockIdx.x >> 1;
  const int s    = blockIdx.x & 1;
  const int tid  = threadIdx.x;
  const int w    = tid >> 6;            // wave 0..7
  const int lane = tid & 63;
  const int quad = lane >> 4;
  const int c    = lane & 15;

  __shared__ short sEdge[E_ + 1];
  __shared__ int   sCnt;
  __shared__ int   sFi[32];
  __shared__ __align__(16) u16 xl[32][72];     // x_t tile (stride 144B)
  __shared__ __align__(16) u16 aggl[32][136];  // GCN aggregate (272B rows)
  __shared__ __align__(16) u16 gelF[32][264];  // FULL ge (528B rows)
  __shared__ __align__(16) u16 hl[32][136];    // own 128 h-cols

  // ---- runtime dtype probe (bf16 vs f32 storage), proven R3 ----
  int plaus = 0;
  {
    const u16* q = (const u16*)Wg;
#pragma unroll 8
    for (int i = 0; i < 512; ++i) {
      float a = fabsf(bf2f(q[i]));
      plaus += (a > 1e-4f && a < 0.3f) ? 1 : 0;
    }
  }
  const int bf = (plaus >= 450) ? 1 : 0;

  if (tid == 0) sCnt = 0;
  if (tid < 32) sFi[tid] = fi[tid] - 1;
  __syncthreads();
  if (edst[tid] == node) {            // E_ == 512 == blockDim
    int q = atomicAdd(&sCnt, 1);
    sEdge[q] = (short)esrc[tid];
  }
  __syncthreads();
  if (tid == 0) sEdge[sCnt] = (short)node;   // append self-loop
  __syncthreads();
  const int cntS = sCnt + 1;
  const float invdeg = 1.0f / (float)cntS;

  // ---- weights -> register MFMA B-fragments (once) ----
  // B-frag (16x16x32): col = lane&15, k = quad*8 + j
  // phase B: wave computes ge col-tiles tA (its phase-C tile) and tB
  const int tA = 8 * s + w, tB = 8 * (1 - s) + w;
  s8v BgA[4], BgB[4];
#pragma unroll
  for (int kt = 0; kt < 4; ++kt) {
    s8v fa, fb;
#pragma unroll
    for (int j = 0; j < 8; ++j) {
      fa[j] = (short)f2bf(ldin(Wg, (size_t)(kt * 32 + quad * 8 + j) * H_ + 16 * tA + c, bf));
      fb[j] = (short)f2bf(ldin(Wg, (size_t)(kt * 32 + quad * 8 + j) * H_ + 16 * tB + c, bf));
    }
    BgA[kt] = fa; BgB[kt] = fb;
  }
  // phase C: wave's H-col = 128s + 16w + c
  const int hcol = 128 * s + 16 * w + c;
  s8v Bih_[3][2], Bhh_[3][8];
#pragma unroll
  for (int gt = 0; gt < 3; ++gt) {
    const size_t bih_base = (size_t)node * G3_ * D_ + (size_t)(gt * H_ + hcol) * D_;
    const size_t bhh_base = (size_t)node * G3_ * H_ + (size_t)(gt * H_ + hcol) * H_;
#pragma unroll
    for (int kt = 0; kt < 2; ++kt) {
      s8v f;
#pragma unroll
      for (int j = 0; j < 8; ++j)
        f[j] = (short)f2bf(ldin(Wih, bih_base + kt * 32 + quad * 8 + j, bf));
      Bih_[gt][kt] = f;
    }
#pragma unroll
    for (int kt = 0; kt < 8; ++kt) {
      s8v f;
#pragma unroll
      for (int j = 0; j < 8; ++j)
        f[j] = (short)f2bf(ldin(Whh, bhh_base + kt * 32 + quad * 8 + j, bf));
      Bhh_[gt][kt] = f;
    }
  }
  // phase D: wave's EMB col = 16w + c; K-range = own 128 h-cols
  const int ecol = 16 * w + c;
  s8v Bl_[4];
  {
    const size_t bl_base = (size_t)node * EMB_ * H_ + (size_t)ecol * H_ + 128 * s;
#pragma unroll
    for (int kt = 0; kt < 4; ++kt) {
      s8v f;
#pragma unroll
      for (int j = 0; j < 8; ++j)
        f[j] = (short)f2bf(ldin(Wlast, bl_base + kt * 32 + quad * 8 + j, bf));
      Bl_[kt] = f;
    }
  }
  const float bgcA = ldin(bg, 16 * tA + c, bf);
  const float bgcB = ldin(bg, 16 * tB + c, bf);
  float bihv[3], bhhv[3];
#pragma unroll
  for (int gt = 0; gt < 3; ++gt) {
    bihv[gt] = ldin(bih, (size_t)node * G3_ + gt * H_ + hcol, bf);
    bhhv[gt] = ldin(bhh, (size_t)node * G3_ + gt * H_ + hcol, bf);
  }
  const float blc = (s == 0) ? ldin(blast, (size_t)node * EMB_ + ecol, bf) : 0.f;

  // partial-sum buffers: ep[sib][parity][node][row][f] (f32)
  const size_t NODE_SZ = (size_t)B_ * EMB_;
#define EPB(sib, par) (ep + (((size_t)(sib) * 2 + (par)) * N_ + node) * NODE_SZ)

  // ---- init: e0 = x0 @ Winit^T + binit into parity-0; s=1 writes zeros ----
  {
    const int row = tid >> 4, d0 = (tid & 15) * 4;
#pragma unroll
    for (int k = 0; k < 4; ++k)
      xl[row][d0 + k] = f2bf(ldin(x, ((size_t)row * N_ + node) * (T_ * D_) + d0 + k, bf));
  }
  __syncthreads();
  {
    const int row = tid >> 4, f0 = (tid & 15) * 8;
    float* dst = EPB(s, 0) + row * EMB_ + f0;
    if (s == 0) {
#pragma unroll
      for (int ff = 0; ff < 8; ++ff) {
        const int f = f0 + ff;
        float acc = ldin(binit, (size_t)node * EMB_ + f, bf);
        const size_t wb = ((size_t)node * EMB_ + f) * D_;
#pragma unroll 8
        for (int d = 0; d < D_; ++d) acc += bf2f(xl[row][d]) * ldin(Winit, wb + d, bf);
        dst[ff] = acc;
      }
    } else {
#pragma unroll
      for (int ff = 0; ff < 8; ++ff) dst[ff] = 0.f;
    }
  }

  int phase = 0;
#pragma unroll 1
  for (int t = 0; t <= T_; ++t) {
    // ---- global barrier (128 blocks): partials of step t-1 visible ----
    __syncthreads();
    ++phase;
    if (tid == 0) {
      __threadfence();
      atomicAdd(gctr, 1);
      while (__hip_atomic_load(gctr, __ATOMIC_RELAXED, __HIP_MEMORY_SCOPE_AGENT) < 128 * phase)
        __builtin_amdgcn_s_sleep(2);
      __threadfence();
    }
    __syncthreads();
    const int par = t & 1;

    // ---- out rows produced at step t-1 (e_new = tanh(p0+p1)) ----
    if (s == 0 && t >= 1) {
      const int row = tid >> 4, f0 = (tid & 15) * 8;
      if (sFi[row] == t - 1) {
        const float* p0 = EPB(0, par) + row * EMB_ + f0;
        const float* p1 = EPB(1, par) + row * EMB_ + f0;
#pragma unroll
        for (int k = 0; k < 8; ++k)
          out[(size_t)row * (N_ * EMB_) + node * EMB_ + f0 + k] = tanh_f(p0[k] + p1[k]);
      }
    }
    if (t == T_) break;

    // ---- phase A: x_t tile + GCN gather (consumer-side tanh) ----
    {
      const int row = tid >> 4, d0 = (tid & 15) * 4;
#pragma unroll
      for (int k = 0; k < 4; ++k)
        xl[row][d0 + k] = f2bf(ldin(x, ((size_t)row * N_ + node) * (T_ * D_) + (size_t)t * D_ + d0 + k, bf));
    }
    {
      const int row = tid >> 4, f0 = (tid & 15) * 8;
      const float* b0 = ep + ((size_t)(0 * 2 + par) * N_) * NODE_SZ + row * EMB_ + f0;
      const float* b1 = ep + ((size_t)(1 * 2 + par) * N_) * NODE_SZ + row * EMB_ + f0;
      float acc[8];
#pragma unroll
      for (int k = 0; k < 8; ++k) acc[k] = 0.f;
      if (t == 0) {  // e0 is NOT tanh'd in the reference
        for (int i = 0; i < cntS; ++i) {
          const size_t so = (size_t)(int)sEdge[i] * NODE_SZ;
          f4v a0 = *(const f4v*)(b0 + so),     a1 = *(const f4v*)(b0 + so + 4);
          f4v c0 = *(const f4v*)(b1 + so),     c1 = *(const f4v*)(b1 + so + 4);
#pragma unroll
          for (int k = 0; k < 4; ++k) { acc[k] += a0[k] + c0[k]; acc[4 + k] += a1[k] + c1[k]; }
        }
      } else {
        for (int i = 0; i < cntS; ++i) {
          const size_t so = (size_t)(int)sEdge[i] * NODE_SZ;
          f4v a0 = *(const f4v*)(b0 + so),     a1 = *(const f4v*)(b0 + so + 4);
          f4v c0 = *(const f4v*)(b1 + so),     c1 = *(const f4v*)(b1 + so + 4);
#pragma unroll
          for (int k = 0; k < 4; ++k) {
            acc[k]     += tanh_f(a0[k] + c0[k]);
            acc[4 + k] += tanh_f(a1[k] + c1[k]);
          }
        }
      }
      s8v pk;
#pragma unroll
      for (int k = 0; k < 8; ++k) pk[k] = (short)f2bf(acc[k] * invdeg);
      *(s8v*)&aggl[row][f0] = pk;
    }
    __syncthreads();

    // ---- phase B: full ge = tanh(agg @ Wg + bg); wave -> tiles tA, tB ----
    float gevA[2][4];
#pragma unroll
    for (int rh = 0; rh < 2; ++rh) {
      s8v a[4];
#pragma unroll
      for (int kt = 0; kt < 4; ++kt) a[kt] = *(const s8v*)&aggl[16 * rh + c][kt * 32 + quad * 8];
      f4v accA = {0.f, 0.f, 0.f, 0.f}, accB = {0.f, 0.f, 0.f, 0.f};
#pragma unroll
      for (int kt = 0; kt < 4; ++kt) {
        accA = MFMA16(a[kt], BgA[kt], accA);
        accB = MFMA16(a[kt], BgB[kt], accB);
      }
#pragma unroll
      for (int i = 0; i < 4; ++i) {
        float vA = tanh_f(accA[i] + bgcA);
        float vB = tanh_f(accB[i] + bgcB);
        gevA[rh][i] = vA;
        gelF[16 * rh + quad * 4 + i][16 * tA + c] = f2bf(vA);
        gelF[16 * rh + quad * 4 + i][16 * tB + c] = f2bf(vB);
      }
    }
    __syncthreads();

    // ---- phase C: GRU gates for wave's H-col (both row halves) ----
#pragma unroll
    for (int rh = 0; rh < 2; ++rh) {
      f4v aR = {0,0,0,0}, aZ = {0,0,0,0}, aXn = {0,0,0,0}, aHn = {0,0,0,0};
#pragma unroll
      for (int kt = 0; kt < 2; ++kt) {
        s8v a = *(const s8v*)&xl[16 * rh + c][kt * 32 + quad * 8];
        aR  = MFMA16(a, Bih_[0][kt], aR);
        aZ  = MFMA16(a, Bih_[1][kt], aZ);
        aXn = MFMA16(a, Bih_[2][kt], aXn);
      }
#pragma unroll
      for (int kt = 0; kt < 8; ++kt) {
        s8v a = *(const s8v*)&gelF[16 * rh + c][kt * 32 + quad * 8];
        aR  = MFMA16(a, Bhh_[0][kt], aR);
        aZ  = MFMA16(a, Bhh_[1][kt], aZ);
        aHn = MFMA16(a, Bhh_[2][kt], aHn);
      }
#pragma unroll
      for (int i = 0; i < 4; ++i) {
        float r_ = sigm_f(aR[i] + bihv[0] + bhhv[0]);
        float z_ = sigm_f(aZ[i] + bihv[1] + bhhv[1]);
        float ng = tanh_f(aXn[i] + bihv[2] + r_ * (aHn[i] + bhhv[2]));
        float h  = (1.f - z_) * ng + z_ * gevA[rh][i];
        hl[16 * rh + quad * 4 + i][16 * w + c] = f2bf(h);
      }
    }
    __syncthreads();

    // ---- phase D: PARTIAL e_new over own K=128 h-cols (+bias if s==0) ----
    {
      float* eo = EPB(s, (t + 1) & 1);
#pragma unroll
      for (int rh = 0; rh < 2; ++rh) {
        f4v aE = {0, 0, 0, 0};
#pragma unroll
        for (int kt = 0; kt < 4; ++kt) {
          s8v a = *(const s8v*)&hl[16 * rh + c][kt * 32 + quad * 8];
          aE = MFMA16(a, Bl_[kt], aE);
        }
#pragma unroll
        for (int i = 0; i < 4; ++i) {
          const int row = 16 * rh + quad * 4 + i;
          eo[(size_t)row * EMB_ + ecol] = aE[i] + blc;
        }
      }
    }
  }
#undef EPB
}

extern "C" void kernel_launch(void* const* d_in, const int* in_sizes, int n_in,
                              void* d_out, int out_size, void* d_ws, size_t ws_size,
                              hipStream_t stream) {
  const void* x     = d_in[0];
  const int*  fi    = (const int*)d_in[1];
  const int*  esrc  = (const int*)d_in[2];
  const int*  edst  = (const int*)d_in[3];
  const void* Winit = d_in[4];
  const void* binit = d_in[5];
  const void* Wg    = d_in[6];
  const void* bg    = d_in[7];
  const void* Wih   = d_in[8];
  const void* Whh   = d_in[9];
  const void* bih   = d_in[10];
  const void* bhh   = d_in[11];
  const void* Wlast = d_in[12];
  const void* blast = d_in[13];

  // d_ws: [0,4096) barrier counter (zeroed); then partial buffers
  // ep[sib 2][parity 2][N][B][EMB] f32 = 8 MB
  int*   gctr = (int*)d_ws;
  float* ep   = (float*)((char*)d_ws + 4096);
  hipMemsetAsync(d_ws, 0, 4096, stream);

  ggru_kernel<<<128, 512, 0, stream>>>(
      x, fi, esrc, edst, Winit, binit, Wg, bg, Wih, Whh, bih, bhh,
      Wlast, blast, (float*)d_out, gctr, ep);
}